// Round 13
// baseline (848.370 us; speedup 1.0000x reference)
//
#include <hip/hip_runtime.h>
#include <cstdint>
#include <cstddef>

typedef __bf16 bf16;
typedef __bf16 bf16x4 __attribute__((ext_vector_type(4)));
typedef __bf16 bf16x8 __attribute__((ext_vector_type(8)));
typedef float f32x4 __attribute__((ext_vector_type(4)));

__device__ __forceinline__ void gload_lds16(const bf16* g, bf16* l) {
    __builtin_amdgcn_global_load_lds((const __attribute__((address_space(1))) void*)g,
                                     (__attribute__((address_space(3))) void*)l, 16, 0, 0);
}

// ---------------- f32 -> bf16 conversion ----------------
__global__ void cvt_f32_bf16_kernel(const float* __restrict__ in, bf16* __restrict__ outp, size_t n) {
    const size_t i = ((size_t)blockIdx.x * 256 + threadIdx.x) * 8;
    if (i >= n) return;
    const float4 a = *(const float4*)(in + i);
    const float4 b = *(const float4*)(in + i + 4);
    bf16x8 o;
    o[0] = (bf16)a.x; o[1] = (bf16)a.y; o[2] = (bf16)a.z; o[3] = (bf16)a.w;
    o[4] = (bf16)b.x; o[5] = (bf16)b.y; o[6] = (bf16)b.z; o[7] = (bf16)b.w;
    *(bf16x8*)(outp + i) = o;
}

// ---------------- all 4 weight transposes in one launch ----------------
__global__ void wtrans_all_kernel(const float* __restrict__ W1, bf16* __restrict__ T1,
                                  const float* __restrict__ W2, bf16* __restrict__ T2,
                                  const float* __restrict__ W3, bf16* __restrict__ T3,
                                  const float* __restrict__ Wo, bf16* __restrict__ To)
{
    __shared__ bf16 tile[64][65];
    const int id = blockIdx.x;
    const int t = threadIdx.x;
    const float* W; bf16* T; int K, N, kb, nb;
    if (id < 216)      { W = W1; T = T1; K = 1152; N = 768;  const int r = id;       kb = r % 18; nb = r / 18; }
    else if (id < 312) { W = W2; T = T2; K = 768;  N = 512;  const int r = id - 216; kb = r % 12; nb = r / 12; }
    else if (id < 344) { W = W3; T = T3; K = 512;  N = 256;  const int r = id - 312; kb = r % 8;  nb = r / 8;  }
    else               { W = Wo; T = To; K = 256;  N = 1152; const int r = id - 344; kb = r % 4;  nb = r / 4;  }
    const int k0 = kb << 6;
    const int n0 = nb << 6;
#pragma unroll
    for (int i = 0; i < 16; ++i) {
        const int flat = i * 256 + t;
        const int r = flat >> 6;
        const int c = flat & 63;
        tile[c][r] = (bf16)W[(size_t)(k0 + r) * N + n0 + c];
    }
    __syncthreads();
#pragma unroll
    for (int i = 0; i < 16; ++i) {
        const int flat = i * 256 + t;
        const int r = flat >> 6;
        const int c = flat & 63;
        T[(size_t)(n0 + r) * K + k0 + c] = tile[r][c];
    }
}

// XCD-aware bijective swizzle (requires nwg % 8 == 0)
__device__ __forceinline__ int xcd_swz(int bid, int nwg) {
    return (bid & 7) * (nwg >> 3) + (bid >> 3);
}

// ---------------- GEMM (bf16 A): C = A @ Bt^T + bias, optional exact GELU ----------------
__global__ void gemm_bf16_kernel(const bf16* __restrict__ A, const bf16* __restrict__ Bt,
                                 const float* __restrict__ bias, bf16* __restrict__ C,
                                 int K, int N, int nx, int do_gelu)
{
    __shared__ bf16 Alds[128 * 64];
    __shared__ bf16 Blds[128 * 64];
    const int t = threadIdx.x;
    const int w = t >> 6;
    const int l = t & 63;
    const int l15 = l & 15, l4 = l >> 4;
    const int wgid = xcd_swz(blockIdx.x, gridDim.x);
    const int mblk = wgid / nx;
    const int nblk = wgid - mblk * nx;
    const int m0 = mblk << 7;
    const int n0 = nblk << 7;
    const int wm = (w >> 1) << 6;
    const int wn = (w & 1) << 6;

    f32x4 acc[4][4] = {};

    int sr[4], sg[4];
#pragma unroll
    for (int i = 0; i < 4; ++i) {
        const int flat = i * 256 + t;
        sr[i] = flat >> 3;
        sg[i] = ((flat & 7) ^ (sr[i] & 7)) << 3;
    }

    for (int k0 = 0; k0 < K; k0 += 64) {
#pragma unroll
        for (int i = 0; i < 4; ++i) {
            gload_lds16(A + (size_t)(m0 + sr[i]) * K + (k0 + sg[i]),
                        &Alds[(size_t)(i * 256 + (w << 6)) << 3]);
            gload_lds16(Bt + (size_t)(n0 + sr[i]) * K + (k0 + sg[i]),
                        &Blds[(size_t)(i * 256 + (w << 6)) << 3]);
        }
        __syncthreads();
#pragma unroll
        for (int kk = 0; kk < 2; ++kk) {
            bf16x8 af[4], bfv[4];
#pragma unroll
            for (int i = 0; i < 4; ++i) {
                const int r = wm + (i << 4) + l15;
                const int g = (kk << 2) + l4;
                af[i] = *(const bf16x8*)&Alds[(r << 6) + ((g ^ (r & 7)) << 3)];
                const int rn = wn + (i << 4) + l15;
                bfv[i] = *(const bf16x8*)&Blds[(rn << 6) + ((g ^ (rn & 7)) << 3)];
            }
#pragma unroll
            for (int i = 0; i < 4; ++i)
#pragma unroll
                for (int j = 0; j < 4; ++j)
                    acc[i][j] = __builtin_amdgcn_mfma_f32_16x16x32_bf16(af[i], bfv[j], acc[i][j], 0, 0, 0);
        }
        __syncthreads();
    }

#pragma unroll
    for (int i = 0; i < 4; ++i) {
        const int mb = m0 + wm + (i << 4) + (l4 << 2);
#pragma unroll
        for (int j = 0; j < 4; ++j) {
            const int col = n0 + wn + (j << 4) + l15;
            const float bv = bias[col];
#pragma unroll
            for (int r = 0; r < 4; ++r) {
                float v = acc[i][j][r] + bv;
                if (do_gelu) v = 0.5f * v * (1.0f + erff(v * 0.70710678118654752f));
                C[(size_t)(mb + r) * N + col] = (bf16)v;
            }
        }
    }
}

// ---------------- GEMM with fused column-pool (output layer) ----------------
__global__ void gemm_pool_kernel(const bf16* __restrict__ A, const bf16* __restrict__ Bt,
                                 const float* __restrict__ bias, bf16* __restrict__ C,
                                 int K, int N, int nx, float* __restrict__ ppart)
{
    __shared__ bf16 Alds[128 * 64];
    __shared__ bf16 Blds[128 * 64];
    __shared__ float psum[2][128];
    const int t = threadIdx.x;
    const int w = t >> 6;
    const int l = t & 63;
    const int l15 = l & 15, l4 = l >> 4;
    const int wgid = xcd_swz(blockIdx.x, gridDim.x);
    const int mblk = wgid / nx;
    const int nblk = wgid - mblk * nx;
    const int m0 = mblk << 7;
    const int n0 = nblk << 7;
    const int wm = (w >> 1) << 6;
    const int wn = (w & 1) << 6;

    f32x4 acc[4][4] = {};

    int sr[4], sg[4];
#pragma unroll
    for (int i = 0; i < 4; ++i) {
        const int flat = i * 256 + t;
        sr[i] = flat >> 3;
        sg[i] = ((flat & 7) ^ (sr[i] & 7)) << 3;
    }

    for (int k0 = 0; k0 < K; k0 += 64) {
#pragma unroll
        for (int i = 0; i < 4; ++i) {
            gload_lds16(A + (size_t)(m0 + sr[i]) * K + (k0 + sg[i]),
                        &Alds[(size_t)(i * 256 + (w << 6)) << 3]);
            gload_lds16(Bt + (size_t)(n0 + sr[i]) * K + (k0 + sg[i]),
                        &Blds[(size_t)(i * 256 + (w << 6)) << 3]);
        }
        __syncthreads();
#pragma unroll
        for (int kk = 0; kk < 2; ++kk) {
            bf16x8 af[4], bfv[4];
#pragma unroll
            for (int i = 0; i < 4; ++i) {
                const int r = wm + (i << 4) + l15;
                const int g = (kk << 2) + l4;
                af[i] = *(const bf16x8*)&Alds[(r << 6) + ((g ^ (r & 7)) << 3)];
                const int rn = wn + (i << 4) + l15;
                bfv[i] = *(const bf16x8*)&Blds[(rn << 6) + ((g ^ (rn & 7)) << 3)];
            }
#pragma unroll
            for (int i = 0; i < 4; ++i)
#pragma unroll
                for (int j = 0; j < 4; ++j)
                    acc[i][j] = __builtin_amdgcn_mfma_f32_16x16x32_bf16(af[i], bfv[j], acc[i][j], 0, 0, 0);
        }
        __syncthreads();
    }

#pragma unroll
    for (int i = 0; i < 4; ++i) {
        const int mb = m0 + wm + (i << 4) + (l4 << 2);
#pragma unroll
        for (int j = 0; j < 4; ++j) {
            const int col = n0 + wn + (j << 4) + l15;
            const float bv = bias[col];
#pragma unroll
            for (int r = 0; r < 4; ++r)
                C[(size_t)(mb + r) * N + col] = (bf16)(acc[i][j][r] + bv);
        }
    }

#pragma unroll
    for (int j = 0; j < 4; ++j) {
        float cs = 0.f;
#pragma unroll
        for (int i = 0; i < 4; ++i)
#pragma unroll
            for (int r = 0; r < 4; ++r) cs += acc[i][j][r];
        cs += __shfl_xor(cs, 16, 64);
        cs += __shfl_xor(cs, 32, 64);
        if (l4 == 0) psum[w >> 1][((w & 1) << 6) + (j << 4) + l15] = cs;
    }
    __syncthreads();
    if (t < 128) {
        const int col = n0 + t;
        ppart[(size_t)mblk * N + col] = psum[0][t] + psum[1][t] + 128.0f * bias[col];
    }
}

// ---------------- LayerNorms ----------------
__global__ void ln768_kernel(bf16* __restrict__ H, const float* __restrict__ g,
                             const float* __restrict__ be)
{
    const int t = threadIdx.x;
    const int w = t >> 6, l = t & 63;
    bf16* hp = H + ((size_t)blockIdx.x * 4 + w) * 768;
    float v[12];
    float s1 = 0.f, s2 = 0.f;
#pragma unroll
    for (int gi = 0; gi < 3; ++gi) {
        const bf16x4 hv = *(const bf16x4*)(hp + gi * 256 + l * 4);
#pragma unroll
        for (int e = 0; e < 4; ++e) {
            const float f = (float)hv[e];
            v[gi * 4 + e] = f; s1 += f; s2 += f * f;
        }
    }
#pragma unroll
    for (int m = 1; m < 64; m <<= 1) { s1 += __shfl_xor(s1, m, 64); s2 += __shfl_xor(s2, m, 64); }
    const float mu = s1 * (1.0f / 768.0f);
    const float rstd = rsqrtf(s2 * (1.0f / 768.0f) - mu * mu + 1e-5f);
#pragma unroll
    for (int gi = 0; gi < 3; ++gi) {
        const float4 gv = *(const float4*)(g + gi * 256 + l * 4);
        const float4 bv = *(const float4*)(be + gi * 256 + l * 4);
        bf16x4 o;
        o[0] = (bf16)((v[gi * 4 + 0] - mu) * rstd * gv.x + bv.x);
        o[1] = (bf16)((v[gi * 4 + 1] - mu) * rstd * gv.y + bv.y);
        o[2] = (bf16)((v[gi * 4 + 2] - mu) * rstd * gv.z + bv.z);
        o[3] = (bf16)((v[gi * 4 + 3] - mu) * rstd * gv.w + bv.w);
        *(bf16x4*)(hp + gi * 256 + l * 4) = o;
    }
}

__global__ void ln512_kernel(bf16* __restrict__ H, const float* __restrict__ g,
                             const float* __restrict__ be)
{
    const int t = threadIdx.x;
    const int w = t >> 6, l = t & 63;
    bf16* hp = H + ((size_t)blockIdx.x * 4 + w) * 512;
    const bf16x8 hv = *(const bf16x8*)(hp + l * 8);
    float v[8];
    float s1 = 0.f, s2 = 0.f;
#pragma unroll
    for (int e = 0; e < 8; ++e) { v[e] = (float)hv[e]; s1 += v[e]; s2 += v[e] * v[e]; }
#pragma unroll
    for (int m = 1; m < 64; m <<= 1) { s1 += __shfl_xor(s1, m, 64); s2 += __shfl_xor(s2, m, 64); }
    const float mu = s1 * (1.0f / 512.0f);
    const float rstd = rsqrtf(s2 * (1.0f / 512.0f) - mu * mu + 1e-5f);
    const float4 g0 = *(const float4*)(g + l * 8);
    const float4 g1 = *(const float4*)(g + l * 8 + 4);
    const float4 b0 = *(const float4*)(be + l * 8);
    const float4 b1 = *(const float4*)(be + l * 8 + 4);
    bf16x8 o;
    o[0] = (bf16)((v[0] - mu) * rstd * g0.x + b0.x);
    o[1] = (bf16)((v[1] - mu) * rstd * g0.y + b0.y);
    o[2] = (bf16)((v[2] - mu) * rstd * g0.z + b0.z);
    o[3] = (bf16)((v[3] - mu) * rstd * g0.w + b0.w);
    o[4] = (bf16)((v[4] - mu) * rstd * g1.x + b1.x);
    o[5] = (bf16)((v[5] - mu) * rstd * g1.y + b1.y);
    o[6] = (bf16)((v[6] - mu) * rstd * g1.z + b1.z);
    o[7] = (bf16)((v[7] - mu) * rstd * g1.w + b1.w);
    *(bf16x8*)(hp + l * 8) = o;
}

__global__ void ln256_kernel(bf16* __restrict__ H, const float* __restrict__ g,
                             const float* __restrict__ be)
{
    const int t = threadIdx.x;
    const int rloc = t >> 5, l = t & 31;
    bf16* hp = H + ((size_t)blockIdx.x * 8 + rloc) * 256;
    const bf16x8 hv = *(const bf16x8*)(hp + l * 8);
    float v[8];
    float s1 = 0.f, s2 = 0.f;
#pragma unroll
    for (int e = 0; e < 8; ++e) { v[e] = (float)hv[e]; s1 += v[e]; s2 += v[e] * v[e]; }
#pragma unroll
    for (int m = 1; m < 32; m <<= 1) { s1 += __shfl_xor(s1, m, 64); s2 += __shfl_xor(s2, m, 64); }
    const float mu = s1 * (1.0f / 256.0f);
    const float rstd = rsqrtf(s2 * (1.0f / 256.0f) - mu * mu + 1e-5f);
    const float4 g0 = *(const float4*)(g + l * 8);
    const float4 g1 = *(const float4*)(g + l * 8 + 4);
    const float4 b0 = *(const float4*)(be + l * 8);
    const float4 b1 = *(const float4*)(be + l * 8 + 4);
    bf16x8 o;
    o[0] = (bf16)((v[0] - mu) * rstd * g0.x + b0.x);
    o[1] = (bf16)((v[1] - mu) * rstd * g0.y + b0.y);
    o[2] = (bf16)((v[2] - mu) * rstd * g0.z + b0.z);
    o[3] = (bf16)((v[3] - mu) * rstd * g0.w + b0.w);
    o[4] = (bf16)((v[4] - mu) * rstd * g1.x + b1.x);
    o[5] = (bf16)((v[5] - mu) * rstd * g1.y + b1.y);
    o[6] = (bf16)((v[6] - mu) * rstd * g1.z + b1.z);
    o[7] = (bf16)((v[7] - mu) * rstd * g1.w + b1.w);
    *(bf16x8*)(hp + l * 8) = o;
}

// ---------------- SE MLP (pool finish: sum 72 m-block partials per batch) ----------------
__global__ void se_kernel(const float* __restrict__ ppart,
                          const float* __restrict__ w1, const float* __restrict__ b1,
                          const float* __restrict__ w2, const float* __restrict__ b2,
                          float* __restrict__ sbuf)
{
    const int b = blockIdx.x, t = threadIdx.x;
    __shared__ float p[1152];
    __shared__ float t1[144];
    for (int c = t; c < 1152; c += 256) {
        float s = 0.f;
#pragma unroll 8
        for (int j = 0; j < 72; ++j) s += ppart[(size_t)(b * 72 + j) * 1152 + c];
        p[c] = s * (1.0f / 9216.0f);
    }
    __syncthreads();
    if (t < 144) {
        float a = b1[t];
        for (int k = 0; k < 1152; ++k) a += p[k] * w1[k * 144 + t];
        t1[t] = a > 0.f ? a : 0.f;
    }
    __syncthreads();
    for (int c = t; c < 1152; c += 256) {
        float a = b2[c];
#pragma unroll 8
        for (int k = 0; k < 144; ++k) a += t1[k] * w2[k * 1152 + c];
        sbuf[b * 1152 + c] = 1.0f / (1.0f + expf(-a));
    }
}

// ---------------- windowed self-attention ----------------
// 39.0KB LDS -> 4 blocks/CU: Sp shrunk to 2 slots (waves 2/3 accumulate into 0/1),
// output staged 8 rows at a time (4 passes) through ostg.
__device__ __forceinline__ int fswz(int r) { return (r & 7) ^ ((r >> 3) & 3); }

#define OSTG_STRIDE 388

__global__ void attn_kernel(const bf16* __restrict__ Y, const float* __restrict__ sbuf,
                            float* __restrict__ out)
{
    // 24576 (yw) + 12416 (ostg8 / Sp[2] union) + 2048 (P) = 39040 B -> 4 blocks/CU
    __shared__ __align__(16) char smem[24576 + 12416 + 2048];
    bf16*  yw   = (bf16*)smem;                       // [32][384] swizzled
    float* SpF  = (float*)(smem + 24576);            // [2][32][33] (score phase only)
    float* ostg = (float*)(smem + 24576);            // [8][388]   (PV phase only)
    bf16*  P    = (bf16*)(smem + 24576 + 12416);     // [32][32]

    const int t = threadIdx.x;
    const int w = t >> 6, l = t & 63;
    const int l15 = l & 15, l4 = l >> 4;
    const int wdx = blockIdx.x, b = blockIdx.y;

    const bf16* Yp = Y + ((size_t)b * 9216 + (size_t)wdx * 32) * 1152;
    const float* sv = sbuf + b * 1152;
    float* op = out + ((size_t)b * 9216 + (size_t)wdx * 32) * 1152;

    auto stage_chunk = [&](int cc) {
#pragma unroll
        for (int i = 0; i < 6; ++i) {
            const int flat = i * 256 + t;
            const int r = flat / 48;
            const int gg = flat - r * 48;
            const int c0 = cc * 384 + gg * 8;
            const bf16x8 yv = *(const bf16x8*)(Yp + (size_t)r * 1152 + c0);
            const float4 sa = *(const float4*)(sv + c0);
            const float4 sb = *(const float4*)(sv + c0 + 4);
            bf16x8 ov;
            ov[0] = (bf16)((float)yv[0] * sa.x);
            ov[1] = (bf16)((float)yv[1] * sa.y);
            ov[2] = (bf16)((float)yv[2] * sa.z);
            ov[3] = (bf16)((float)yv[3] * sa.w);
            ov[4] = (bf16)((float)yv[4] * sb.x);
            ov[5] = (bf16)((float)yv[5] * sb.y);
            ov[6] = (bf16)((float)yv[6] * sb.z);
            ov[7] = (bf16)((float)yv[7] * sb.w);
            *(bf16x8*)&yw[((r * 48) + (gg ^ fswz(r))) << 3] = ov;
        }
    };

    // ---- scores: S = Yw @ Yw^T, k-split across 4 waves ----
    f32x4 acc[2][2] = {};
    for (int cc = 0; cc < 3; ++cc) {
        if (cc) __syncthreads();
        stage_chunk(cc);
        __syncthreads();
#pragma unroll
        for (int kkl = 0; kkl < 3; ++kkl) {
            const int g = ((w * 3 + kkl) << 2) + l4;
            bf16x8 af[2];
#pragma unroll
            for (int i = 0; i < 2; ++i) {
                const int r = (i << 4) + l15;
                af[i] = *(const bf16x8*)&yw[((r * 48) + (g ^ fswz(r))) << 3];
            }
#pragma unroll
            for (int i = 0; i < 2; ++i)
#pragma unroll
                for (int j = 0; j < 2; ++j)
                    acc[i][j] = __builtin_amdgcn_mfma_f32_16x16x32_bf16(af[i], af[j], acc[i][j], 0, 0, 0);
        }
    }
    // 2-slot partial reduction: waves 0/1 write, waves 2/3 accumulate
    if (w < 2) {
#pragma unroll
        for (int i = 0; i < 2; ++i)
#pragma unroll
            for (int j = 0; j < 2; ++j)
#pragma unroll
                for (int r = 0; r < 4; ++r)
                    SpF[w * 1056 + ((i << 4) + (l4 << 2) + r) * 33 + (j << 4) + l15] = acc[i][j][r];
    }
    __syncthreads();
    if (w >= 2) {
#pragma unroll
        for (int i = 0; i < 2; ++i)
#pragma unroll
            for (int j = 0; j < 2; ++j)
#pragma unroll
                for (int r = 0; r < 4; ++r)
                    SpF[(w - 2) * 1056 + ((i << 4) + (l4 << 2) + r) * 33 + (j << 4) + l15] += acc[i][j][r];
    }
    __syncthreads();

    // ---- softmax ----
    {
        const int q = t >> 3, u = t & 7;
        float v[4];
#pragma unroll
        for (int e = 0; e < 4; ++e) {
            const int k2 = (u << 2) + e;
            v[e] = (SpF[q * 33 + k2] + SpF[1056 + q * 33 + k2]) * 0.029462782549439483f;
        }
        float mx = fmaxf(fmaxf(v[0], v[1]), fmaxf(v[2], v[3]));
#pragma unroll
        for (int m = 1; m < 8; m <<= 1) mx = fmaxf(mx, __shfl_xor(mx, m, 64));
        float sm = 0.f;
#pragma unroll
        for (int e = 0; e < 4; ++e) { v[e] = expf(v[e] - mx); sm += v[e]; }
#pragma unroll
        for (int m = 1; m < 8; m <<= 1) sm += __shfl_xor(sm, m, 64);
        const float inv = 1.0f / sm;
#pragma unroll
        for (int e = 0; e < 4; ++e) P[(q << 5) + (u << 2) + e] = (bf16)(v[e] * inv);
    }
    __syncthreads();

    bf16x8 pa[2];
#pragma unroll
    for (int i = 0; i < 2; ++i)
        pa[i] = *(const bf16x8*)&P[(((i << 4) + l15) << 5) + (l4 << 3)];

    for (int ci = 0; ci < 3; ++ci) {
        const int cc = (ci == 0) ? 2 : (ci - 1);
        if (ci) {
            __syncthreads();
            stage_chunk(cc);
            __syncthreads();
        }
        f32x4 pacc[2][6] = {};
#pragma unroll
        for (int jn = 0; jn < 6; ++jn) {
            const int nl = w * 96 + (jn << 4) + l15;
            const int gg = nl >> 3, e = nl & 7;
            bf16x8 bv;
#pragma unroll
            for (int j = 0; j < 8; ++j) {
                const int kr = (l4 << 3) + j;
                bv[j] = yw[(((kr * 48) + (gg ^ fswz(kr))) << 3) + e];
            }
#pragma unroll
            for (int i = 0; i < 2; ++i)
                pacc[i][jn] = __builtin_amdgcn_mfma_f32_16x16x32_bf16(pa[i], bv, pacc[i][jn], 0, 0, 0);
        }
        // four 8-row staging passes through ostg (write 2-way-free, read+writeout full lines)
#pragma unroll
        for (int qp = 0; qp < 4; ++qp) {
            if (qp) __syncthreads();   // order vs previous read pass
            if ((l4 >> 1) == (qp & 1)) {
                const int i = qp >> 1;
#pragma unroll
                for (int jn = 0; jn < 6; ++jn)
#pragma unroll
                    for (int r = 0; r < 4; ++r)
                        ostg[(((l4 & 1) << 2) + r) * OSTG_STRIDE + w * 96 + (jn << 4) + l15] =
                            pacc[i][jn][r];
            }
            __syncthreads();
            {
                const int row = t >> 5;                 // 0..7
                const int cb = (t & 31) << 2;           // float offset 0..124
                float* orow = op + (size_t)(row + (qp << 3)) * 1152 + cc * 384;
                const float* srow = &ostg[row * OSTG_STRIDE];
#pragma unroll
                for (int k2 = 0; k2 < 3; ++k2) {
                    const int c = cb + (k2 << 7);
                    *(float4*)(orow + c) = *(const float4*)(srow + c);
                }
            }
        }
        if (ci < 2) __syncthreads();     // ostg/yw reuse ordering before next stage
    }
}

// ---------------- launcher ----------------
extern "C" void kernel_launch(void* const* d_in, const int* in_sizes, int n_in,
                              void* d_out, int out_size, void* d_ws, size_t ws_size,
                              hipStream_t stream)
{
    const float* x   = (const float*)d_in[0];
    const float* W1  = (const float*)d_in[1];
    const float* b1  = (const float*)d_in[2];
    const float* g1  = (const float*)d_in[3];
    const float* be1 = (const float*)d_in[4];
    const float* W2  = (const float*)d_in[5];
    const float* b2  = (const float*)d_in[6];
    const float* g2  = (const float*)d_in[7];
    const float* be2 = (const float*)d_in[8];
    const float* W3  = (const float*)d_in[9];
    const float* b3  = (const float*)d_in[10];
    const float* g3  = (const float*)d_in[11];
    const float* be3 = (const float*)d_in[12];
    const float* Wo  = (const float*)d_in[13];
    const float* bo  = (const float*)d_in[14];
    const float* cw1 = (const float*)d_in[15];
    const float* cb1 = (const float*)d_in[16];
    const float* cw2 = (const float*)d_in[17];
    const float* cb2 = (const float*)d_in[18];
    float* out = (float*)d_out;

    const int M = 8 * 9216;  // 73728 rows
    size_t off = 0;
    auto alloc = [&](size_t nbytes) {
        void* p = (char*)d_ws + off;
        off += (nbytes + 255) & ~(size_t)255;
        return p;
    };
    bf16* Yb  = (bf16*)alloc((size_t)M * 1152 * 2);  // x-bf16 early, Y late (disjoint lifetimes)
    bf16* Hb  = (bf16*)alloc((size_t)M * 768 * 2);   // H1; later reused as H3
    bf16* H2  = (bf16*)alloc((size_t)M * 512 * 2);
    bf16* Wt1 = (bf16*)alloc(768ull * 1152 * 2);
    bf16* Wt2 = (bf16*)alloc(512ull * 768 * 2);
    bf16* Wt3 = (bf16*)alloc(256ull * 512 * 2);
    bf16* Wto = (bf16*)alloc(1152ull * 256 * 2);
    float* ppart = (float*)alloc(576ull * 1152 * 4);
    float* sbuf  = (float*)alloc(8ull * 1152 * 4);
    bf16* Xb = Yb;   // x-bf16 dead before GEMMo writes Y here
    bf16* H1 = Hb;
    bf16* H3 = Hb;

    cvt_f32_bf16_kernel<<<41472, 256, 0, stream>>>(x, Xb, (size_t)M * 1152);
    wtrans_all_kernel<<<416, 256, 0, stream>>>(W1, Wt1, W2, Wt2, W3, Wt3, Wo, Wto);

    gemm_bf16_kernel<<<6 * 576, 256, 0, stream>>>(Xb, Wt1, b1, H1, 1152, 768, 6, 1);
    ln768_kernel<<<M / 4, 256, 0, stream>>>(H1, g1, be1);
    gemm_bf16_kernel<<<4 * 576, 256, 0, stream>>>(H1, Wt2, b2, H2, 768, 512, 4, 1);
    ln512_kernel<<<M / 4, 256, 0, stream>>>(H2, g2, be2);
    gemm_bf16_kernel<<<2 * 576, 256, 0, stream>>>(H2, Wt3, b3, H3, 512, 256, 2, 1);
    ln256_kernel<<<M / 8, 256, 0, stream>>>(H3, g3, be3);
    gemm_pool_kernel<<<9 * 576, 256, 0, stream>>>(H3, Wto, bo, Yb, 256, 1152, 9, ppart);

    se_kernel<<<8, 256, 0, stream>>>(ppart, cw1, cb1, cw2, cb2, sbuf);
    attn_kernel<<<dim3(288, 8), 256, 0, stream>>>(Yb, sbuf, out);
}

// Round 14
// 805.259 us; speedup vs baseline: 1.0535x; 1.0535x over previous
//
#include <hip/hip_runtime.h>
#include <cstdint>
#include <cstddef>

typedef __bf16 bf16;
typedef __bf16 bf16x4 __attribute__((ext_vector_type(4)));
typedef __bf16 bf16x8 __attribute__((ext_vector_type(8)));
typedef float f32x4 __attribute__((ext_vector_type(4)));

__device__ __forceinline__ void gload_lds16(const bf16* g, bf16* l) {
    __builtin_amdgcn_global_load_lds((const __attribute__((address_space(1))) void*)g,
                                     (__attribute__((address_space(3))) void*)l, 16, 0, 0);
}

// ---------------- f32 -> bf16 conversion ----------------
__global__ void cvt_f32_bf16_kernel(const float* __restrict__ in, bf16* __restrict__ outp, size_t n) {
    const size_t i = ((size_t)blockIdx.x * 256 + threadIdx.x) * 8;
    if (i >= n) return;
    const float4 a = *(const float4*)(in + i);
    const float4 b = *(const float4*)(in + i + 4);
    bf16x8 o;
    o[0] = (bf16)a.x; o[1] = (bf16)a.y; o[2] = (bf16)a.z; o[3] = (bf16)a.w;
    o[4] = (bf16)b.x; o[5] = (bf16)b.y; o[6] = (bf16)b.z; o[7] = (bf16)b.w;
    *(bf16x8*)(outp + i) = o;
}

// ---------------- all 4 weight transposes in one launch ----------------
__global__ void wtrans_all_kernel(const float* __restrict__ W1, bf16* __restrict__ T1,
                                  const float* __restrict__ W2, bf16* __restrict__ T2,
                                  const float* __restrict__ W3, bf16* __restrict__ T3,
                                  const float* __restrict__ Wo, bf16* __restrict__ To)
{
    __shared__ bf16 tile[64][65];
    const int id = blockIdx.x;
    const int t = threadIdx.x;
    const float* W; bf16* T; int K, N, kb, nb;
    if (id < 216)      { W = W1; T = T1; K = 1152; N = 768;  const int r = id;       kb = r % 18; nb = r / 18; }
    else if (id < 312) { W = W2; T = T2; K = 768;  N = 512;  const int r = id - 216; kb = r % 12; nb = r / 12; }
    else if (id < 344) { W = W3; T = T3; K = 512;  N = 256;  const int r = id - 312; kb = r % 8;  nb = r / 8;  }
    else               { W = Wo; T = To; K = 256;  N = 1152; const int r = id - 344; kb = r % 4;  nb = r / 4;  }
    const int k0 = kb << 6;
    const int n0 = nb << 6;
#pragma unroll
    for (int i = 0; i < 16; ++i) {
        const int flat = i * 256 + t;
        const int r = flat >> 6;
        const int c = flat & 63;
        tile[c][r] = (bf16)W[(size_t)(k0 + r) * N + n0 + c];
    }
    __syncthreads();
#pragma unroll
    for (int i = 0; i < 16; ++i) {
        const int flat = i * 256 + t;
        const int r = flat >> 6;
        const int c = flat & 63;
        T[(size_t)(n0 + r) * K + k0 + c] = tile[r][c];
    }
}

// XCD-aware bijective swizzle (requires nwg % 8 == 0)
__device__ __forceinline__ int xcd_swz(int bid, int nwg) {
    return (bid & 7) * (nwg >> 3) + (bid >> 3);
}

// ---------------- GEMM (bf16 A): C = A @ Bt^T + bias, optional exact GELU ----------------
__global__ void gemm_bf16_kernel(const bf16* __restrict__ A, const bf16* __restrict__ Bt,
                                 const float* __restrict__ bias, bf16* __restrict__ C,
                                 int K, int N, int nx, int do_gelu)
{
    __shared__ bf16 Alds[128 * 64];
    __shared__ bf16 Blds[128 * 64];
    const int t = threadIdx.x;
    const int w = t >> 6;
    const int l = t & 63;
    const int l15 = l & 15, l4 = l >> 4;
    const int wgid = xcd_swz(blockIdx.x, gridDim.x);
    const int mblk = wgid / nx;
    const int nblk = wgid - mblk * nx;
    const int m0 = mblk << 7;
    const int n0 = nblk << 7;
    const int wm = (w >> 1) << 6;
    const int wn = (w & 1) << 6;

    f32x4 acc[4][4] = {};

    int sr[4], sg[4];
#pragma unroll
    for (int i = 0; i < 4; ++i) {
        const int flat = i * 256 + t;
        sr[i] = flat >> 3;
        sg[i] = ((flat & 7) ^ (sr[i] & 7)) << 3;
    }

    for (int k0 = 0; k0 < K; k0 += 64) {
#pragma unroll
        for (int i = 0; i < 4; ++i) {
            gload_lds16(A + (size_t)(m0 + sr[i]) * K + (k0 + sg[i]),
                        &Alds[(size_t)(i * 256 + (w << 6)) << 3]);
            gload_lds16(Bt + (size_t)(n0 + sr[i]) * K + (k0 + sg[i]),
                        &Blds[(size_t)(i * 256 + (w << 6)) << 3]);
        }
        __syncthreads();
#pragma unroll
        for (int kk = 0; kk < 2; ++kk) {
            bf16x8 af[4], bfv[4];
#pragma unroll
            for (int i = 0; i < 4; ++i) {
                const int r = wm + (i << 4) + l15;
                const int g = (kk << 2) + l4;
                af[i] = *(const bf16x8*)&Alds[(r << 6) + ((g ^ (r & 7)) << 3)];
                const int rn = wn + (i << 4) + l15;
                bfv[i] = *(const bf16x8*)&Blds[(rn << 6) + ((g ^ (rn & 7)) << 3)];
            }
#pragma unroll
            for (int i = 0; i < 4; ++i)
#pragma unroll
                for (int j = 0; j < 4; ++j)
                    acc[i][j] = __builtin_amdgcn_mfma_f32_16x16x32_bf16(af[i], bfv[j], acc[i][j], 0, 0, 0);
        }
        __syncthreads();
    }

#pragma unroll
    for (int i = 0; i < 4; ++i) {
        const int mb = m0 + wm + (i << 4) + (l4 << 2);
#pragma unroll
        for (int j = 0; j < 4; ++j) {
            const int col = n0 + wn + (j << 4) + l15;
            const float bv = bias[col];
#pragma unroll
            for (int r = 0; r < 4; ++r) {
                float v = acc[i][j][r] + bv;
                if (do_gelu) v = 0.5f * v * (1.0f + erff(v * 0.70710678118654752f));
                C[(size_t)(mb + r) * N + col] = (bf16)v;
            }
        }
    }
}

// ---------------- GEMM with fused column-pool (output layer) ----------------
__global__ void gemm_pool_kernel(const bf16* __restrict__ A, const bf16* __restrict__ Bt,
                                 const float* __restrict__ bias, bf16* __restrict__ C,
                                 int K, int N, int nx, float* __restrict__ ppart)
{
    __shared__ bf16 Alds[128 * 64];
    __shared__ bf16 Blds[128 * 64];
    __shared__ float psum[2][128];
    const int t = threadIdx.x;
    const int w = t >> 6;
    const int l = t & 63;
    const int l15 = l & 15, l4 = l >> 4;
    const int wgid = xcd_swz(blockIdx.x, gridDim.x);
    const int mblk = wgid / nx;
    const int nblk = wgid - mblk * nx;
    const int m0 = mblk << 7;
    const int n0 = nblk << 7;
    const int wm = (w >> 1) << 6;
    const int wn = (w & 1) << 6;

    f32x4 acc[4][4] = {};

    int sr[4], sg[4];
#pragma unroll
    for (int i = 0; i < 4; ++i) {
        const int flat = i * 256 + t;
        sr[i] = flat >> 3;
        sg[i] = ((flat & 7) ^ (sr[i] & 7)) << 3;
    }

    for (int k0 = 0; k0 < K; k0 += 64) {
#pragma unroll
        for (int i = 0; i < 4; ++i) {
            gload_lds16(A + (size_t)(m0 + sr[i]) * K + (k0 + sg[i]),
                        &Alds[(size_t)(i * 256 + (w << 6)) << 3]);
            gload_lds16(Bt + (size_t)(n0 + sr[i]) * K + (k0 + sg[i]),
                        &Blds[(size_t)(i * 256 + (w << 6)) << 3]);
        }
        __syncthreads();
#pragma unroll
        for (int kk = 0; kk < 2; ++kk) {
            bf16x8 af[4], bfv[4];
#pragma unroll
            for (int i = 0; i < 4; ++i) {
                const int r = wm + (i << 4) + l15;
                const int g = (kk << 2) + l4;
                af[i] = *(const bf16x8*)&Alds[(r << 6) + ((g ^ (r & 7)) << 3)];
                const int rn = wn + (i << 4) + l15;
                bfv[i] = *(const bf16x8*)&Blds[(rn << 6) + ((g ^ (rn & 7)) << 3)];
            }
#pragma unroll
            for (int i = 0; i < 4; ++i)
#pragma unroll
                for (int j = 0; j < 4; ++j)
                    acc[i][j] = __builtin_amdgcn_mfma_f32_16x16x32_bf16(af[i], bfv[j], acc[i][j], 0, 0, 0);
        }
        __syncthreads();
    }

#pragma unroll
    for (int i = 0; i < 4; ++i) {
        const int mb = m0 + wm + (i << 4) + (l4 << 2);
#pragma unroll
        for (int j = 0; j < 4; ++j) {
            const int col = n0 + wn + (j << 4) + l15;
            const float bv = bias[col];
#pragma unroll
            for (int r = 0; r < 4; ++r)
                C[(size_t)(mb + r) * N + col] = (bf16)(acc[i][j][r] + bv);
        }
    }

#pragma unroll
    for (int j = 0; j < 4; ++j) {
        float cs = 0.f;
#pragma unroll
        for (int i = 0; i < 4; ++i)
#pragma unroll
            for (int r = 0; r < 4; ++r) cs += acc[i][j][r];
        cs += __shfl_xor(cs, 16, 64);
        cs += __shfl_xor(cs, 32, 64);
        if (l4 == 0) psum[w >> 1][((w & 1) << 6) + (j << 4) + l15] = cs;
    }
    __syncthreads();
    if (t < 128) {
        const int col = n0 + t;
        ppart[(size_t)mblk * N + col] = psum[0][t] + psum[1][t] + 128.0f * bias[col];
    }
}

// ---------------- LayerNorms ----------------
__global__ void ln768_kernel(bf16* __restrict__ H, const float* __restrict__ g,
                             const float* __restrict__ be)
{
    const int t = threadIdx.x;
    const int w = t >> 6, l = t & 63;
    bf16* hp = H + ((size_t)blockIdx.x * 4 + w) * 768;
    float v[12];
    float s1 = 0.f, s2 = 0.f;
#pragma unroll
    for (int gi = 0; gi < 3; ++gi) {
        const bf16x4 hv = *(const bf16x4*)(hp + gi * 256 + l * 4);
#pragma unroll
        for (int e = 0; e < 4; ++e) {
            const float f = (float)hv[e];
            v[gi * 4 + e] = f; s1 += f; s2 += f * f;
        }
    }
#pragma unroll
    for (int m = 1; m < 64; m <<= 1) { s1 += __shfl_xor(s1, m, 64); s2 += __shfl_xor(s2, m, 64); }
    const float mu = s1 * (1.0f / 768.0f);
    const float rstd = rsqrtf(s2 * (1.0f / 768.0f) - mu * mu + 1e-5f);
#pragma unroll
    for (int gi = 0; gi < 3; ++gi) {
        const float4 gv = *(const float4*)(g + gi * 256 + l * 4);
        const float4 bv = *(const float4*)(be + gi * 256 + l * 4);
        bf16x4 o;
        o[0] = (bf16)((v[gi * 4 + 0] - mu) * rstd * gv.x + bv.x);
        o[1] = (bf16)((v[gi * 4 + 1] - mu) * rstd * gv.y + bv.y);
        o[2] = (bf16)((v[gi * 4 + 2] - mu) * rstd * gv.z + bv.z);
        o[3] = (bf16)((v[gi * 4 + 3] - mu) * rstd * gv.w + bv.w);
        *(bf16x4*)(hp + gi * 256 + l * 4) = o;
    }
}

__global__ void ln512_kernel(bf16* __restrict__ H, const float* __restrict__ g,
                             const float* __restrict__ be)
{
    const int t = threadIdx.x;
    const int w = t >> 6, l = t & 63;
    bf16* hp = H + ((size_t)blockIdx.x * 4 + w) * 512;
    const bf16x8 hv = *(const bf16x8*)(hp + l * 8);
    float v[8];
    float s1 = 0.f, s2 = 0.f;
#pragma unroll
    for (int e = 0; e < 8; ++e) { v[e] = (float)hv[e]; s1 += v[e]; s2 += v[e] * v[e]; }
#pragma unroll
    for (int m = 1; m < 64; m <<= 1) { s1 += __shfl_xor(s1, m, 64); s2 += __shfl_xor(s2, m, 64); }
    const float mu = s1 * (1.0f / 512.0f);
    const float rstd = rsqrtf(s2 * (1.0f / 512.0f) - mu * mu + 1e-5f);
    const float4 g0 = *(const float4*)(g + l * 8);
    const float4 g1 = *(const float4*)(g + l * 8 + 4);
    const float4 b0 = *(const float4*)(be + l * 8);
    const float4 b1 = *(const float4*)(be + l * 8 + 4);
    bf16x8 o;
    o[0] = (bf16)((v[0] - mu) * rstd * g0.x + b0.x);
    o[1] = (bf16)((v[1] - mu) * rstd * g0.y + b0.y);
    o[2] = (bf16)((v[2] - mu) * rstd * g0.z + b0.z);
    o[3] = (bf16)((v[3] - mu) * rstd * g0.w + b0.w);
    o[4] = (bf16)((v[4] - mu) * rstd * g1.x + b1.x);
    o[5] = (bf16)((v[5] - mu) * rstd * g1.y + b1.y);
    o[6] = (bf16)((v[6] - mu) * rstd * g1.z + b1.z);
    o[7] = (bf16)((v[7] - mu) * rstd * g1.w + b1.w);
    *(bf16x8*)(hp + l * 8) = o;
}

__global__ void ln256_kernel(bf16* __restrict__ H, const float* __restrict__ g,
                             const float* __restrict__ be)
{
    const int t = threadIdx.x;
    const int rloc = t >> 5, l = t & 31;
    bf16* hp = H + ((size_t)blockIdx.x * 8 + rloc) * 256;
    const bf16x8 hv = *(const bf16x8*)(hp + l * 8);
    float v[8];
    float s1 = 0.f, s2 = 0.f;
#pragma unroll
    for (int e = 0; e < 8; ++e) { v[e] = (float)hv[e]; s1 += v[e]; s2 += v[e] * v[e]; }
#pragma unroll
    for (int m = 1; m < 32; m <<= 1) { s1 += __shfl_xor(s1, m, 64); s2 += __shfl_xor(s2, m, 64); }
    const float mu = s1 * (1.0f / 256.0f);
    const float rstd = rsqrtf(s2 * (1.0f / 256.0f) - mu * mu + 1e-5f);
    const float4 g0 = *(const float4*)(g + l * 8);
    const float4 g1 = *(const float4*)(g + l * 8 + 4);
    const float4 b0 = *(const float4*)(be + l * 8);
    const float4 b1 = *(const float4*)(be + l * 8 + 4);
    bf16x8 o;
    o[0] = (bf16)((v[0] - mu) * rstd * g0.x + b0.x);
    o[1] = (bf16)((v[1] - mu) * rstd * g0.y + b0.y);
    o[2] = (bf16)((v[2] - mu) * rstd * g0.z + b0.z);
    o[3] = (bf16)((v[3] - mu) * rstd * g0.w + b0.w);
    o[4] = (bf16)((v[4] - mu) * rstd * g1.x + b1.x);
    o[5] = (bf16)((v[5] - mu) * rstd * g1.y + b1.y);
    o[6] = (bf16)((v[6] - mu) * rstd * g1.z + b1.z);
    o[7] = (bf16)((v[7] - mu) * rstd * g1.w + b1.w);
    *(bf16x8*)(hp + l * 8) = o;
}

// ---------------- SE MLP (pool finish: sum 72 m-block partials per batch) ----------------
__global__ void se_kernel(const float* __restrict__ ppart,
                          const float* __restrict__ w1, const float* __restrict__ b1,
                          const float* __restrict__ w2, const float* __restrict__ b2,
                          float* __restrict__ sbuf)
{
    const int b = blockIdx.x, t = threadIdx.x;
    __shared__ float p[1152];
    __shared__ float t1[144];
    for (int c = t; c < 1152; c += 256) {
        float s = 0.f;
#pragma unroll 8
        for (int j = 0; j < 72; ++j) s += ppart[(size_t)(b * 72 + j) * 1152 + c];
        p[c] = s * (1.0f / 9216.0f);
    }
    __syncthreads();
    if (t < 144) {
        float a = b1[t];
        for (int k = 0; k < 1152; ++k) a += p[k] * w1[k * 144 + t];
        t1[t] = a > 0.f ? a : 0.f;
    }
    __syncthreads();
    for (int c = t; c < 1152; c += 256) {
        float a = b2[c];
#pragma unroll 8
        for (int k = 0; k < 144; ++k) a += t1[k] * w2[k * 1152 + c];
        sbuf[b * 1152 + c] = 1.0f / (1.0f + expf(-a));
    }
}

// ---------------- windowed self-attention (R12-proven: 51.4KB, 16-row ostg) ----------------
__device__ __forceinline__ int fswz(int r) { return (r & 7) ^ ((r >> 3) & 3); }

#define OSTG_STRIDE 388

__global__ void attn_kernel(const bf16* __restrict__ Y, const float* __restrict__ sbuf,
                            float* __restrict__ out)
{
    __shared__ __align__(16) char smem[24576 + 24832 + 2048];
    bf16*  yw   = (bf16*)smem;
    float* SpF  = (float*)(smem + 24576);
    float* ostg = (float*)(smem + 24576);
    bf16*  P    = (bf16*)(smem + 24576 + 24832);

    const int t = threadIdx.x;
    const int w = t >> 6, l = t & 63;
    const int l15 = l & 15, l4 = l >> 4;
    const int wdx = blockIdx.x, b = blockIdx.y;

    const bf16* Yp = Y + ((size_t)b * 9216 + (size_t)wdx * 32) * 1152;
    const float* sv = sbuf + b * 1152;
    float* op = out + ((size_t)b * 9216 + (size_t)wdx * 32) * 1152;

    auto stage_chunk = [&](int cc) {
#pragma unroll
        for (int i = 0; i < 6; ++i) {
            const int flat = i * 256 + t;
            const int r = flat / 48;
            const int gg = flat - r * 48;
            const int c0 = cc * 384 + gg * 8;
            const bf16x8 yv = *(const bf16x8*)(Yp + (size_t)r * 1152 + c0);
            const float4 sa = *(const float4*)(sv + c0);
            const float4 sb = *(const float4*)(sv + c0 + 4);
            bf16x8 ov;
            ov[0] = (bf16)((float)yv[0] * sa.x);
            ov[1] = (bf16)((float)yv[1] * sa.y);
            ov[2] = (bf16)((float)yv[2] * sa.z);
            ov[3] = (bf16)((float)yv[3] * sa.w);
            ov[4] = (bf16)((float)yv[4] * sb.x);
            ov[5] = (bf16)((float)yv[5] * sb.y);
            ov[6] = (bf16)((float)yv[6] * sb.z);
            ov[7] = (bf16)((float)yv[7] * sb.w);
            *(bf16x8*)&yw[((r * 48) + (gg ^ fswz(r))) << 3] = ov;
        }
    };

    f32x4 acc[2][2] = {};
    for (int cc = 0; cc < 3; ++cc) {
        if (cc) __syncthreads();
        stage_chunk(cc);
        __syncthreads();
#pragma unroll
        for (int kkl = 0; kkl < 3; ++kkl) {
            const int g = ((w * 3 + kkl) << 2) + l4;
            bf16x8 af[2];
#pragma unroll
            for (int i = 0; i < 2; ++i) {
                const int r = (i << 4) + l15;
                af[i] = *(const bf16x8*)&yw[((r * 48) + (g ^ fswz(r))) << 3];
            }
#pragma unroll
            for (int i = 0; i < 2; ++i)
#pragma unroll
                for (int j = 0; j < 2; ++j)
                    acc[i][j] = __builtin_amdgcn_mfma_f32_16x16x32_bf16(af[i], af[j], acc[i][j], 0, 0, 0);
        }
    }
#pragma unroll
    for (int i = 0; i < 2; ++i)
#pragma unroll
        for (int j = 0; j < 2; ++j)
#pragma unroll
            for (int r = 0; r < 4; ++r)
                SpF[w * 1056 + ((i << 4) + (l4 << 2) + r) * 33 + (j << 4) + l15] = acc[i][j][r];
    __syncthreads();

    {
        const int q = t >> 3, u = t & 7;
        float v[4];
#pragma unroll
        for (int e = 0; e < 4; ++e) {
            const int k2 = (u << 2) + e;
            v[e] = (SpF[q * 33 + k2] + SpF[1056 + q * 33 + k2] +
                    SpF[2112 + q * 33 + k2] + SpF[3168 + q * 33 + k2]) * 0.029462782549439483f;
        }
        float mx = fmaxf(fmaxf(v[0], v[1]), fmaxf(v[2], v[3]));
#pragma unroll
        for (int m = 1; m < 8; m <<= 1) mx = fmaxf(mx, __shfl_xor(mx, m, 64));
        float sm = 0.f;
#pragma unroll
        for (int e = 0; e < 4; ++e) { v[e] = expf(v[e] - mx); sm += v[e]; }
#pragma unroll
        for (int m = 1; m < 8; m <<= 1) sm += __shfl_xor(sm, m, 64);
        const float inv = 1.0f / sm;
#pragma unroll
        for (int e = 0; e < 4; ++e) P[(q << 5) + (u << 2) + e] = (bf16)(v[e] * inv);
    }
    __syncthreads();

    bf16x8 pa[2];
#pragma unroll
    for (int i = 0; i < 2; ++i)
        pa[i] = *(const bf16x8*)&P[(((i << 4) + l15) << 5) + (l4 << 3)];

    for (int ci = 0; ci < 3; ++ci) {
        const int cc = (ci == 0) ? 2 : (ci - 1);
        if (ci) {
            __syncthreads();
            stage_chunk(cc);
            __syncthreads();
        }
        f32x4 pacc[2][6] = {};
#pragma unroll
        for (int jn = 0; jn < 6; ++jn) {
            const int nl = w * 96 + (jn << 4) + l15;
            const int gg = nl >> 3, e = nl & 7;
            bf16x8 bv;
#pragma unroll
            for (int j = 0; j < 8; ++j) {
                const int kr = (l4 << 3) + j;
                bv[j] = yw[(((kr * 48) + (gg ^ fswz(kr))) << 3) + e];
            }
#pragma unroll
            for (int i = 0; i < 2; ++i)
                pacc[i][jn] = __builtin_amdgcn_mfma_f32_16x16x32_bf16(pa[i], bv, pacc[i][jn], 0, 0, 0);
        }
#pragma unroll
        for (int half = 0; half < 2; ++half) {
            if (half) __syncthreads();
#pragma unroll
            for (int jn = 0; jn < 6; ++jn)
#pragma unroll
                for (int r = 0; r < 4; ++r)
                    ostg[((l4 << 2) + r) * OSTG_STRIDE + w * 96 + (jn << 4) + l15] =
                        pacc[half][jn][r];
            __syncthreads();
            {
                const int row = t >> 4;
                const int cb = (t & 15) << 2;
                float* orow = op + (size_t)(row + (half << 4)) * 1152 + cc * 384;
                const float* srow = &ostg[row * OSTG_STRIDE];
#pragma unroll
                for (int k2 = 0; k2 < 6; ++k2) {
                    const int c = cb + (k2 << 6);
                    *(float4*)(orow + c) = *(const float4*)(srow + c);
                }
            }
        }
        if (ci < 2) __syncthreads();
    }
}

// ---------------- launcher ----------------
extern "C" void kernel_launch(void* const* d_in, const int* in_sizes, int n_in,
                              void* d_out, int out_size, void* d_ws, size_t ws_size,
                              hipStream_t stream)
{
    const float* x   = (const float*)d_in[0];
    const float* W1  = (const float*)d_in[1];
    const float* b1  = (const float*)d_in[2];
    const float* g1  = (const float*)d_in[3];
    const float* be1 = (const float*)d_in[4];
    const float* W2  = (const float*)d_in[5];
    const float* b2  = (const float*)d_in[6];
    const float* g2  = (const float*)d_in[7];
    const float* be2 = (const float*)d_in[8];
    const float* W3  = (const float*)d_in[9];
    const float* b3  = (const float*)d_in[10];
    const float* g3  = (const float*)d_in[11];
    const float* be3 = (const float*)d_in[12];
    const float* Wo  = (const float*)d_in[13];
    const float* bo  = (const float*)d_in[14];
    const float* cw1 = (const float*)d_in[15];
    const float* cb1 = (const float*)d_in[16];
    const float* cw2 = (const float*)d_in[17];
    const float* cb2 = (const float*)d_in[18];
    float* out = (float*)d_out;

    const int M = 8 * 9216;  // 73728 rows
    size_t off = 0;
    auto alloc = [&](size_t nbytes) {
        void* p = (char*)d_ws + off;
        off += (nbytes + 255) & ~(size_t)255;
        return p;
    };
    bf16* Yb  = (bf16*)alloc((size_t)M * 1152 * 2);  // x-bf16 early, Y late (disjoint lifetimes)
    bf16* Hb  = (bf16*)alloc((size_t)M * 768 * 2);   // H1; later reused as H3
    bf16* H2  = (bf16*)alloc((size_t)M * 512 * 2);
    bf16* Wt1 = (bf16*)alloc(768ull * 1152 * 2);
    bf16* Wt2 = (bf16*)alloc(512ull * 768 * 2);
    bf16* Wt3 = (bf16*)alloc(256ull * 512 * 2);
    bf16* Wto = (bf16*)alloc(1152ull * 256 * 2);
    float* ppart = (float*)alloc(576ull * 1152 * 4);
    float* sbuf  = (float*)alloc(8ull * 1152 * 4);
    bf16* Xb = Yb;   // x-bf16 dead before GEMMo writes Y here
    bf16* H1 = Hb;
    bf16* H3 = Hb;

    cvt_f32_bf16_kernel<<<41472, 256, 0, stream>>>(x, Xb, (size_t)M * 1152);
    wtrans_all_kernel<<<416, 256, 0, stream>>>(W1, Wt1, W2, Wt2, W3, Wt3, Wo, Wto);

    gemm_bf16_kernel<<<6 * 576, 256, 0, stream>>>(Xb, Wt1, b1, H1, 1152, 768, 6, 1);
    ln768_kernel<<<M / 4, 256, 0, stream>>>(H1, g1, be1);
    gemm_bf16_kernel<<<4 * 576, 256, 0, stream>>>(H1, Wt2, b2, H2, 768, 512, 4, 1);
    ln512_kernel<<<M / 4, 256, 0, stream>>>(H2, g2, be2);
    gemm_bf16_kernel<<<2 * 576, 256, 0, stream>>>(H2, Wt3, b3, H3, 512, 256, 2, 1);
    ln256_kernel<<<M / 8, 256, 0, stream>>>(H3, g3, be3);
    gemm_pool_kernel<<<9 * 576, 256, 0, stream>>>(H3, Wto, bo, Yb, 256, 1152, 9, ppart);

    se_kernel<<<8, 256, 0, stream>>>(ppart, cw1, cb1, cw2, cb2, sbuf);
    attn_kernel<<<dim3(288, 8), 256, 0, stream>>>(Yb, sbuf, out);
}